// Round 6
// baseline (136.292 us; speedup 1.0000x reference)
//
#include <hip/hip_runtime.h>
#include <math.h>

#define N_E   32
#define NUP   16
#define N_I   128
#define H_S   512
#define F_LEN 1544      // 3*512 + 2*4
#define N_K   16

typedef float f32x4 __attribute__((ext_vector_type(4)));

// workspace layout (float offsets)
#define WS_SH0   0                      // [32][512] ping
#define WS_SH1   16384                  // [32][512] pong
#define WS_DH0   32768                  // [32][32][4] ping
#define WS_DH1   36864                  // [32][32][4] pong
#define WS_ENN   40960                  // [32][128] eN_norm
#define WS_DETS  45056                  // [32]

// ---------------------------------------------------------------------------
// Init: eN, eN_norm, sh0, dh0.  grid 16 x 256
__global__ __launch_bounds__(256) void k_init(const float* __restrict__ ep,
                                              const float* __restrict__ nuc,
                                              float* __restrict__ ws) {
    float* sh  = ws + WS_SH0;
    float* dh  = ws + WS_DH0;
    float* eNn = ws + WS_ENN;
    int g = blockIdx.x * 256 + threadIdx.x;       // 0..4095
    {
        int j = g >> 7, m = g & 127;              // eN part: 32*128 = 4096
        float dx = ep[j*3+0] - nuc[m*3+0];
        float dy = ep[j*3+1] - nuc[m*3+1];
        float dz = ep[j*3+2] - nuc[m*3+2];
        float nr = sqrtf(dx*dx + dy*dy + dz*dz);
        eNn[j*N_I + m] = nr;
        sh[j*H_S + 3*m + 0] = dx;
        sh[j*H_S + 3*m + 1] = dy;
        sh[j*H_S + 3*m + 2] = dz;
        sh[j*H_S + 384 + m] = nr;
    }
    if (g < N_E * N_E) {
        int a = g >> 5, b = g & 31;
        float dx = ep[a*3+0] - ep[b*3+0];
        float dy = ep[a*3+1] - ep[b*3+1];
        float dz = ep[a*3+2] - ep[b*3+2];
        float nr = sqrtf(dx*dx + dy*dy + dz*dz);
        float* d = dh + (a*N_E + b)*4;
        d[0] = dx; d[1] = dy; d[2] = dz; d[3] = nr;
    }
}

// ---------------------------------------------------------------------------
// N-split matvec, max-MLP variant. Grid (n, cg) = 32 x 16 = 512 blocks
// (2 per CU, all 256 CUs), 256 threads. Block owns 32 output columns
// [cg*32, cg*32+32). Thread t: rgrp = t>>3 (row offset 0..31),
// lane8 = t&7 (float4 column group). Rows r = i*32 + rgrp, 48 iters,
// unroll 16 -> 16 float4 (16 KB/wave) in flight. Tail rows 1536..1543.
// NT: nontemporal loads for layers that are never re-read (0,1), so L3
// retains layer 2 for its second pass.
template<bool NT>
__global__ __launch_bounds__(256) void k_mv(const float* __restrict__ V,
                                            const float* __restrict__ sh_in,
                                            float* __restrict__ sh_out,
                                            const float* __restrict__ dh_in,
                                            float* __restrict__ dh_out,
                                            const float* __restrict__ bv,
                                            const float* __restrict__ Wm,
                                            const float* __restrict__ cv,
                                            int li) {
    __shared__ float fv[F_LEN];
    __shared__ f32x4 part4[32][8];
    int n = blockIdx.x, cg = blockIdx.y, t = threadIdx.x;

    // ---- build f-vector in LDS (two 256-wide passes) -----------------------
    #pragma unroll
    for (int base = 0; base < 512; base += 256) {
        int c = base + t;
        float up = 0.f, dn = 0.f;
        #pragma unroll
        for (int m = 0; m < 16; ++m)  up += sh_in[m*H_S + c];
        #pragma unroll
        for (int m = 16; m < 32; ++m) dn += sh_in[m*H_S + c];
        fv[c]        = sh_in[n*H_S + c];
        fv[512 + c]  = up * 0.0625f;
        fv[1024 + c] = dn * 0.0625f;
    }
    if (t < 4) {
        float s = 0.f;
        #pragma unroll
        for (int j = 0; j < 16; ++j) s += dh_in[(n*N_E + j)*4 + t];
        fv[1536 + t] = s * 0.0625f;
    } else if (t < 8) {
        int i = t - 4; float s = 0.f;
        #pragma unroll
        for (int j = 16; j < 32; ++j) s += dh_in[(n*N_E + j)*4 + i];
        fv[1540 + i] = s * 0.0625f;
    }
    __syncthreads();

    // ---- stream V[li,n,:, cg*32 + lane8*4 .. +3] ---------------------------
    int rgrp = t >> 3, lane8 = t & 7;
    const float* Vb = V + ((size_t)(li*N_E + n)*F_LEN)*H_S + cg*32 + lane8*4;
    f32x4 acc = {0.f, 0.f, 0.f, 0.f};
    #pragma unroll 16
    for (int i = 0; i < 48; ++i) {
        int r = i*32 + rgrp;
        f32x4 v4;
        if (NT) v4 = __builtin_nontemporal_load(
                         reinterpret_cast<const f32x4*>(Vb + (size_t)r * H_S));
        else    v4 = *reinterpret_cast<const f32x4*>(Vb + (size_t)r * H_S);
        float f = fv[r];
        acc.x = fmaf(v4.x, f, acc.x);
        acc.y = fmaf(v4.y, f, acc.y);
        acc.z = fmaf(v4.z, f, acc.z);
        acc.w = fmaf(v4.w, f, acc.w);
    }
    if (rgrp < 8) {                                  // tail rows 1536..1543
        int r = 1536 + rgrp;
        f32x4 v4;
        if (NT) v4 = __builtin_nontemporal_load(
                         reinterpret_cast<const f32x4*>(Vb + (size_t)r * H_S));
        else    v4 = *reinterpret_cast<const f32x4*>(Vb + (size_t)r * H_S);
        float f = fv[r];
        acc.x = fmaf(v4.x, f, acc.x);
        acc.y = fmaf(v4.y, f, acc.y);
        acc.z = fmaf(v4.z, f, acc.z);
        acc.w = fmaf(v4.w, f, acc.w);
    }
    part4[rgrp][lane8] = acc;
    __syncthreads();

    // ---- finish: 32-way sum, tanh+bias+residual ----------------------------
    if (t < 8) {
        f32x4 s = {0.f, 0.f, 0.f, 0.f};
        #pragma unroll
        for (int g = 0; g < 32; ++g) {
            f32x4 p = part4[g][t];
            s.x += p.x; s.y += p.y; s.z += p.z; s.w += p.w;
        }
        int col = cg*32 + t*4;
        const float* bvp = bv + ((size_t)li*N_E + n)*H_S + col;
        const float* sip = sh_in + n*H_S + col;
        float* sop = sh_out + n*H_S + col;
        sop[0] = tanhf(s.x + bvp[0]) + sip[0];
        sop[1] = tanhf(s.y + bvp[1]) + sip[1];
        sop[2] = tanhf(s.z + bvp[2]) + sip[2];
        sop[3] = tanhf(s.w + bvp[3]) + sip[3];
    }
    // ---- tiny dh update (one cg per electron) ------------------------------
    if (cg == 0 && t >= 128 && t < 256) {
        int q = t - 128, j2 = q >> 2, ii = q & 3;
        const float* Wp = Wm + ((((size_t)li*N_E + n)*N_E + j2)*4 + ii)*4;
        const float* dr = dh_in + (n*N_E + j2)*4;
        float a2 = Wp[0]*dr[0] + Wp[1]*dr[1] + Wp[2]*dr[2] + Wp[3]*dr[3];
        dh_out[(n*N_E + j2)*4 + ii] =
            tanhf(a2 + cv[(((size_t)li*N_E + n)*N_E + j2)*4 + ii]) + dr[ii];
    }
}

// ---------------------------------------------------------------------------
// Fused env + phi + 16x16 determinant. Block b: k = b>>1, spin = b&1.
__global__ __launch_bounds__(256) void k_envdet(const float* __restrict__ fw,
                                                const float* __restrict__ fb,
                                                const float* __restrict__ pw,
                                                const float* __restrict__ sw,
                                                const float* __restrict__ sh,
                                                const float* __restrict__ eNn,
                                                float* __restrict__ dets) {
    int b = blockIdx.x, k = b >> 1, sp = b & 1, base = sp * 16;
    int t = threadIdx.x;
    int i = base + (t >> 4);
    int j = base + (t & 15);

    const float* wv = fw + ((size_t)k*N_E + i)*H_S;
    const float* sv = sh + (size_t)j*H_S;
    float fd = 0.f;
    #pragma unroll 8
    for (int c = 0; c < H_S; c += 4) {
        float4 a  = *reinterpret_cast<const float4*>(wv + c);
        float4 bz = *reinterpret_cast<const float4*>(sv + c);
        fd += a.x*bz.x + a.y*bz.y + a.z*bz.z + a.w*bz.w;
    }
    fd += fb[k*N_E + i];

    const float* pv = pw + ((size_t)k*N_E + i)*N_I;
    const float* sg = sw + ((size_t)k*N_E + i)*N_I;
    const float* rn = eNn + (size_t)j*N_I;
    float env = 0.f;
    #pragma unroll 4
    for (int m = 0; m < N_I; ++m)
        env = fmaf(pv[m], expf(-fabsf(sg[m]) * rn[m]), env);

    __shared__ float phi[16][16];
    phi[t >> 4][t & 15] = fd * env;
    __syncthreads();

    if (t < 64) {
        int lane = t;
        int r = lane & 15;
        float a[16];
        #pragma unroll
        for (int c = 0; c < 16; ++c) a[c] = phi[r][c];
        bool used = (lane >= 16);
        float prod = 1.f;
        int sigma[16];
        #pragma unroll
        for (int p = 0; p < 16; ++p) {
            float v = used ? -1.f : fabsf(a[p]);
            int idx = lane;
            #pragma unroll
            for (int off = 32; off; off >>= 1) {
                float ov = __shfl_xor(v, off);
                int   oi = __shfl_xor(idx, off);
                if (ov > v || (ov == v && oi < idx)) { v = ov; idx = oi; }
            }
            int q = idx;
            float pvt = __shfl(a[p], q);
            prod *= pvt;
            sigma[p] = q;
            float factor = (!used && lane != q && pvt != 0.f) ? (a[p] / pvt) : 0.f;
            #pragma unroll
            for (int c = p; c < 16; ++c) {
                float pr = __shfl(a[c], q);
                a[c] -= factor * pr;
            }
            if (lane == q) used = true;
        }
        if (lane == 0) {
            int inv = 0;
            #pragma unroll
            for (int x = 0; x < 16; ++x)
                #pragma unroll
                for (int y = x + 1; y < 16; ++y) inv += (sigma[x] > sigma[y]) ? 1 : 0;
            dets[b] = prod * ((inv & 1) ? -1.f : 1.f);
        }
    }
}

// ---------------------------------------------------------------------------
__global__ void k_out(const float* __restrict__ dets, const float* __restrict__ omega,
                      float* __restrict__ out) {
    if (threadIdx.x == 0) {
        float s = 0.f;
        for (int k = 0; k < N_K; ++k)
            s += omega[k] * dets[2*k + 0] * dets[2*k + 1];
        out[0] = s;
    }
}

// ---------------------------------------------------------------------------
extern "C" void kernel_launch(void* const* d_in, const int* in_sizes, int n_in,
                              void* d_out, int out_size, void* d_ws, size_t ws_size,
                              hipStream_t stream) {
    const float* ep  = (const float*)d_in[0];   // [32,3]
    const float* nuc = (const float*)d_in[1];   // [128,3]
    const float* V   = (const float*)d_in[2];   // [4,32,1544,512]
    const float* bv  = (const float*)d_in[3];   // [4,32,512]
    const float* Wm  = (const float*)d_in[4];   // [4,32,32,4,4]
    const float* cv  = (const float*)d_in[5];   // [4,32,32,4]
    const float* fw  = (const float*)d_in[6];   // [16,32,512]
    const float* fb  = (const float*)d_in[7];   // [16,32]
    const float* pw  = (const float*)d_in[8];   // [16,32,128]
    const float* sw  = (const float*)d_in[9];   // [16,32,128]
    const float* om  = (const float*)d_in[10];  // [16]
    float* out = (float*)d_out;
    float* ws  = (float*)d_ws;

    float* shb[2] = { ws + WS_SH0, ws + WS_SH1 };
    float* dhb[2] = { ws + WS_DH0, ws + WS_DH1 };
    float* eNn    = ws + WS_ENN;
    float* dets   = ws + WS_DETS;

    k_init<<<dim3(16), dim3(256), 0, stream>>>(ep, nuc, ws);

    // layer sequence quirk: 0, 1, 2, then 2 again; sh/dh ping-pong
    for (int a = 0; a < 4; ++a) {
        int li = (a < 3) ? a : 2;
        if (a < 2)
            k_mv<true><<<dim3(N_E, 16), dim3(256), 0, stream>>>(
                V, shb[a & 1], shb[(a + 1) & 1], dhb[a & 1], dhb[(a + 1) & 1],
                bv, Wm, cv, li);
        else
            k_mv<false><<<dim3(N_E, 16), dim3(256), 0, stream>>>(
                V, shb[a & 1], shb[(a + 1) & 1], dhb[a & 1], dhb[(a + 1) & 1],
                bv, Wm, cv, li);
    }
    // after 4 layers, final sh is in buf0
    k_envdet<<<dim3(2 * N_K), dim3(256), 0, stream>>>(
        fw, fb, pw, sw, shb[0], eNn, dets);
    k_out<<<dim3(1), dim3(64), 0, stream>>>(dets, om, out);
}

// Round 7
// 128.576 us; speedup vs baseline: 1.0600x; 1.0600x over previous
//
#include <hip/hip_runtime.h>
#include <math.h>

#define N_E   32
#define NUP   16
#define N_I   128
#define H_S   512
#define F_LEN 1544      // 3*512 + 2*4
#define N_K   16

typedef float f32x4 __attribute__((ext_vector_type(4)));

// workspace layout (float offsets)
#define WS_SH0   0                      // [32][512] ping
#define WS_SH1   16384                  // [32][512] pong
#define WS_DH0   32768                  // [32][32][4] ping
#define WS_DH1   36864                  // [32][32][4] pong
#define WS_ENN   40960                  // [32][128] eN_norm
#define WS_DETS  45056                  // [32]
#define WS_CNT   45088                  // 1 int (tail counter for envdet)

// ---------------------------------------------------------------------------
// N-split matvec, R4 geometry. Block (n, cgi in 0..3) owns output columns
// [cgi*128, cgi*128+128); streams all F_LEN rows of V[li,n] for that slice.
// PHASE 0: first layer — builds features locally from ep/nuc (no k_init),
//          writes eNn for envdet, computes dh0 locally for the dh update.
// PHASE 1: middle layers. PHASE 2: last layer — also resets envdet counter.
template<int PHASE>
__global__ __launch_bounds__(512) void k_mv(const float* __restrict__ V,
                                            const float* __restrict__ ep,
                                            const float* __restrict__ nuc,
                                            const float* __restrict__ sh_in,
                                            float* __restrict__ sh_out,
                                            const float* __restrict__ dh_in,
                                            float* __restrict__ dh_out,
                                            const float* __restrict__ bv,
                                            const float* __restrict__ Wm,
                                            const float* __restrict__ cv,
                                            float* __restrict__ ws,
                                            int li) {
    __shared__ float fv[F_LEN];
    __shared__ f32x4 part4[16][32];
    __shared__ float eps[N_E * 3];
    int n = blockIdx.x, cgi = blockIdx.y, t = threadIdx.x;

    // ---- build f-vector in LDS (fv[0..512) == sh_in[n][:] for the residual)
    if (PHASE == 0) {
        if (t < 96) eps[t] = ep[t];
        __syncthreads();
        float self, up, dn;
        if (t < 384) {                       // eN vector components
            int comp = t % 3;                // t = m_nuc*3 + comp
            float nv = nuc[t];
            self = eps[n*3 + comp] - nv;
            float mu = 0.f, md = 0.f;
            #pragma unroll
            for (int m2 = 0; m2 < 16; ++m2)  mu += eps[m2*3 + comp] - nv;
            #pragma unroll
            for (int m2 = 16; m2 < 32; ++m2) md += eps[m2*3 + comp] - nv;
            up = mu * 0.0625f; dn = md * 0.0625f;
        } else {                             // eN norms
            int m = t - 384;
            float nx = nuc[m*3], ny = nuc[m*3+1], nz = nuc[m*3+2];
            float su = 0.f, sd = 0.f, own = 0.f;
            #pragma unroll
            for (int m2 = 0; m2 < 32; ++m2) {
                float dx = eps[m2*3]-nx, dy = eps[m2*3+1]-ny, dz = eps[m2*3+2]-nz;
                float nr = sqrtf(dx*dx + dy*dy + dz*dz);
                if (m2 < 16) su += nr; else sd += nr;
                if (m2 == n) own = nr;
            }
            self = own; up = su * 0.0625f; dn = sd * 0.0625f;
            if (cgi == 0) (ws + WS_ENN)[n*N_I + m] = own;   // for envdet
        }
        fv[t] = self; fv[512 + t] = up; fv[1024 + t] = dn;
        if (t < 8) {                         // dh0 means from ep directly
            int comp = t & 3; int j0 = (t < 4) ? 0 : 16;
            float s = 0.f;
            for (int j = j0; j < j0 + 16; ++j) {
                if (comp < 3) s += eps[n*3 + comp] - eps[j*3 + comp];
                else {
                    float dx = eps[n*3]-eps[j*3], dy = eps[n*3+1]-eps[j*3+1],
                          dz = eps[n*3+2]-eps[j*3+2];
                    s += sqrtf(dx*dx + dy*dy + dz*dz);
                }
            }
            fv[1536 + t] = s * 0.0625f;
        }
    } else {
        float upv = 0.f, dnv = 0.f;
        #pragma unroll
        for (int m = 0; m < 16; ++m)  upv += sh_in[m*H_S + t];
        #pragma unroll
        for (int m = 16; m < 32; ++m) dnv += sh_in[m*H_S + t];
        fv[t]        = sh_in[n*H_S + t];
        fv[512 + t]  = upv * 0.0625f;
        fv[1024 + t] = dnv * 0.0625f;
        if (t < 8) {
            int comp = t & 3; int j0 = (t < 4) ? 0 : 16;
            float s = 0.f;
            #pragma unroll
            for (int j = 0; j < 16; ++j) s += dh_in[(n*N_E + j0 + j)*4 + comp];
            fv[1536 + t] = s * 0.0625f;
        }
    }
    if (PHASE == 2 && n == 0 && cgi == 0 && t == 0)
        *((int*)(ws + WS_CNT)) = 0;          // reset envdet tail counter
    __syncthreads();

    // ---- stream V[li,n,:, cgi*128 + colg*4 .. +3] --------------------------
    int rbase = ((t >> 6) << 1) | ((t >> 5) & 1);   // 0..15
    int colg  = t & 31;
    const float* Vb = V + ((size_t)(li*N_E + n)*F_LEN)*H_S + cgi*128 + colg*4;
    f32x4 acc = {0.f, 0.f, 0.f, 0.f};
    #pragma unroll 8
    for (int i = 0; i < 96; ++i) {
        int r = i*16 + rbase;
        f32x4 v4 = *reinterpret_cast<const f32x4*>(Vb + (size_t)r * H_S);
        float f = fv[r];
        acc.x = fmaf(v4.x, f, acc.x);
        acc.y = fmaf(v4.y, f, acc.y);
        acc.z = fmaf(v4.z, f, acc.z);
        acc.w = fmaf(v4.w, f, acc.w);
    }
    if (rbase < 8) {                                 // tail rows 1536..1543
        int r = 1536 + rbase;
        f32x4 v4 = *reinterpret_cast<const f32x4*>(Vb + (size_t)r * H_S);
        float f = fv[r];
        acc.x = fmaf(v4.x, f, acc.x);
        acc.y = fmaf(v4.y, f, acc.y);
        acc.z = fmaf(v4.z, f, acc.z);
        acc.w = fmaf(v4.w, f, acc.w);
    }
    part4[rbase][colg] = acc;
    __syncthreads();

    // ---- finish: 16-way sum, tanh+bias+residual (residual from fv) ---------
    if (t < 32) {
        f32x4 s = {0.f, 0.f, 0.f, 0.f};
        #pragma unroll
        for (int g = 0; g < 16; ++g) {
            f32x4 p = part4[g][t];
            s.x += p.x; s.y += p.y; s.z += p.z; s.w += p.w;
        }
        int col = cgi*128 + t*4;
        const float* bvp = bv + ((size_t)li*N_E + n)*H_S + col;
        float* sop = sh_out + n*H_S + col;
        sop[0] = tanhf(s.x + bvp[0]) + fv[col+0];
        sop[1] = tanhf(s.y + bvp[1]) + fv[col+1];
        sop[2] = tanhf(s.z + bvp[2]) + fv[col+2];
        sop[3] = tanhf(s.w + bvp[3]) + fv[col+3];
    }
    // ---- tiny dh update (one cgi per electron) -----------------------------
    if (cgi == 0 && t >= 256 && t < 384) {
        int q = t - 256, j2 = q >> 2, ii = q & 3;
        const float* Wp = Wm + ((((size_t)li*N_E + n)*N_E + j2)*4 + ii)*4;
        float dr0, dr1, dr2, dr3;
        if (PHASE == 0) {
            dr0 = eps[n*3]   - eps[j2*3];
            dr1 = eps[n*3+1] - eps[j2*3+1];
            dr2 = eps[n*3+2] - eps[j2*3+2];
            dr3 = sqrtf(dr0*dr0 + dr1*dr1 + dr2*dr2);
        } else {
            const float* drp = dh_in + (n*N_E + j2)*4;
            dr0 = drp[0]; dr1 = drp[1]; dr2 = drp[2]; dr3 = drp[3];
        }
        float a2 = Wp[0]*dr0 + Wp[1]*dr1 + Wp[2]*dr2 + Wp[3]*dr3;
        float drsel = (ii == 0) ? dr0 : (ii == 1) ? dr1 : (ii == 2) ? dr2 : dr3;
        dh_out[(n*N_E + j2)*4 + ii] =
            tanhf(a2 + cv[(((size_t)li*N_E + n)*N_E + j2)*4 + ii]) + drsel;
    }
}

// ---------------------------------------------------------------------------
// Fused env + phi + 16x16 determinant + final weighted sum (32-block tail).
__global__ __launch_bounds__(256) void k_envdet(const float* __restrict__ fw,
                                                const float* __restrict__ fb,
                                                const float* __restrict__ pw,
                                                const float* __restrict__ sw,
                                                const float* __restrict__ omega,
                                                float* __restrict__ ws,
                                                float* __restrict__ out) {
    const float* sh  = ws + WS_SH0;     // final sh in buf0 after 4 layers
    const float* eNn = ws + WS_ENN;
    float* dets = ws + WS_DETS;
    int* cnt = (int*)(ws + WS_CNT);
    int b = blockIdx.x, k = b >> 1, sp = b & 1, base = sp * 16;
    int t = threadIdx.x;
    int i = base + (t >> 4);
    int j = base + (t & 15);

    const float* wv = fw + ((size_t)k*N_E + i)*H_S;
    const float* sv = sh + (size_t)j*H_S;
    float fd = 0.f;
    #pragma unroll 8
    for (int c = 0; c < H_S; c += 4) {
        float4 a  = *reinterpret_cast<const float4*>(wv + c);
        float4 bz = *reinterpret_cast<const float4*>(sv + c);
        fd += a.x*bz.x + a.y*bz.y + a.z*bz.z + a.w*bz.w;
    }
    fd += fb[k*N_E + i];

    const float* pv = pw + ((size_t)k*N_E + i)*N_I;
    const float* sg = sw + ((size_t)k*N_E + i)*N_I;
    const float* rn = eNn + (size_t)j*N_I;
    float env = 0.f;
    #pragma unroll 4
    for (int m = 0; m < N_I; ++m)
        env = fmaf(pv[m], expf(-fabsf(sg[m]) * rn[m]), env);

    __shared__ float phi[16][16];
    phi[t >> 4][t & 15] = fd * env;
    __syncthreads();

    if (t < 64) {
        int lane = t;
        int r = lane & 15;
        float a[16];
        #pragma unroll
        for (int c = 0; c < 16; ++c) a[c] = phi[r][c];
        bool used = (lane >= 16);
        float prod = 1.f;
        int sigma[16];
        #pragma unroll
        for (int p = 0; p < 16; ++p) {
            float v = used ? -1.f : fabsf(a[p]);
            int idx = lane;
            #pragma unroll
            for (int off = 32; off; off >>= 1) {
                float ov = __shfl_xor(v, off);
                int   oi = __shfl_xor(idx, off);
                if (ov > v || (ov == v && oi < idx)) { v = ov; idx = oi; }
            }
            int q = idx;
            float pvt = __shfl(a[p], q);
            prod *= pvt;
            sigma[p] = q;
            float factor = (!used && lane != q && pvt != 0.f) ? (a[p] / pvt) : 0.f;
            #pragma unroll
            for (int c = p; c < 16; ++c) {
                float pr = __shfl(a[c], q);
                a[c] -= factor * pr;
            }
            if (lane == q) used = true;
        }
        if (lane == 0) {
            int inv = 0;
            #pragma unroll
            for (int x = 0; x < 16; ++x)
                #pragma unroll
                for (int y = x + 1; y < 16; ++y) inv += (sigma[x] > sigma[y]) ? 1 : 0;
            dets[b] = prod * ((inv & 1) ? -1.f : 1.f);
        }
    }
    __syncthreads();

    // ---- last-block tail: final weighted sum (32 atomics total) ------------
    __shared__ int tailFlag;
    if (t == 0) {
        __threadfence();                   // release dets[b]
        int old = atomicAdd(cnt, 1);
        tailFlag = (old == 31) ? 1 : 0;
    }
    __syncthreads();
    if (tailFlag && t == 0) {
        __threadfence();                   // acquire all dets
        float s = 0.f;
        for (int kk = 0; kk < N_K; ++kk)
            s += omega[kk] * dets[2*kk + 0] * dets[2*kk + 1];
        out[0] = s;
    }
}

// ---------------------------------------------------------------------------
extern "C" void kernel_launch(void* const* d_in, const int* in_sizes, int n_in,
                              void* d_out, int out_size, void* d_ws, size_t ws_size,
                              hipStream_t stream) {
    const float* ep  = (const float*)d_in[0];   // [32,3]
    const float* nuc = (const float*)d_in[1];   // [128,3]
    const float* V   = (const float*)d_in[2];   // [4,32,1544,512]
    const float* bv  = (const float*)d_in[3];   // [4,32,512]
    const float* Wm  = (const float*)d_in[4];   // [4,32,32,4,4]
    const float* cv  = (const float*)d_in[5];   // [4,32,32,4]
    const float* fw  = (const float*)d_in[6];   // [16,32,512]
    const float* fb  = (const float*)d_in[7];   // [16,32]
    const float* pw  = (const float*)d_in[8];   // [16,32,128]
    const float* sw  = (const float*)d_in[9];   // [16,32,128]
    const float* om  = (const float*)d_in[10];  // [16]
    float* out = (float*)d_out;
    float* ws  = (float*)d_ws;

    float* shb[2] = { ws + WS_SH0, ws + WS_SH1 };
    float* dhb[2] = { ws + WS_DH0, ws + WS_DH1 };

    // layer sequence quirk: 0, 1, 2, then 2 again; sh/dh ping-pong
    // a=0: out buf1; a=1: 1->0; a=2: 0->1; a=3: 1->0  => final sh in buf0
    k_mv<0><<<dim3(N_E, 4), dim3(512), 0, stream>>>(
        V, ep, nuc, shb[0], shb[1], dhb[0], dhb[1], bv, Wm, cv, ws, 0);
    k_mv<1><<<dim3(N_E, 4), dim3(512), 0, stream>>>(
        V, ep, nuc, shb[1], shb[0], dhb[1], dhb[0], bv, Wm, cv, ws, 1);
    k_mv<1><<<dim3(N_E, 4), dim3(512), 0, stream>>>(
        V, ep, nuc, shb[0], shb[1], dhb[0], dhb[1], bv, Wm, cv, ws, 2);
    k_mv<2><<<dim3(N_E, 4), dim3(512), 0, stream>>>(
        V, ep, nuc, shb[1], shb[0], dhb[1], dhb[0], bv, Wm, cv, ws, 2);

    k_envdet<<<dim3(2 * N_K), dim3(256), 0, stream>>>(fw, fb, pw, sw, om, ws, out);
}